// Round 4
// baseline (369.054 us; speedup 1.0000x reference)
//
#include <hip/hip_runtime.h>

#define N_NODES 20000
#define E_EDGES 640000
#define F_DIM 128
#define RBF_DIM 64
#define T_TYPES 5
#define NSEG (N_NODES * T_TYPES)

typedef __attribute__((ext_vector_type(8))) short short8;
typedef __attribute__((ext_vector_type(4))) float f32x4;

__device__ __forceinline__ float silu_f(float x) { return x / (1.0f + __expf(-x)); }

__device__ __forceinline__ ushort f2bf(float f) {
  unsigned u = __float_as_uint(f);
  u += 0x7fffu + ((u >> 16) & 1u);
  return (ushort)(u >> 16);
}
__device__ __forceinline__ float bf2f(ushort u) {
  return __uint_as_float(((unsigned)u) << 16);
}
// packed fp32->bf16 (RTNE): src0 -> D[15:0], src1 -> D[31:16]
__device__ __forceinline__ unsigned cvt_pk(float lo, float hi) {
  unsigned r;
  asm("v_cvt_pk_bf16_f32 %0, %1, %2" : "=v"(r) : "v"(lo), "v"(hi));
  return r;
}
union S8U4 {
  short8 s;
  unsigned u[4];
};

// ---------------- weight prep: fp32 -> bf16 (w1,w2,qw,kw,vw) ----------------
__global__ __launch_bounds__(256) void prep_kernel(
    const float* __restrict__ w1, const float* __restrict__ w2,
    const float* __restrict__ qw, const float* __restrict__ kw,
    const float* __restrict__ vw, ushort* __restrict__ w1b,
    ushort* __restrict__ w2b, ushort* __restrict__ qwb,
    ushort* __restrict__ kwb, ushort* __restrict__ vwb) {
  int i = blockIdx.x * 256 + threadIdx.x;
  if (i < F_DIM * RBF_DIM) w1b[i] = f2bf(w1[i]);
  if (i < F_DIM * F_DIM) {
    w2b[i] = f2bf(w2[i]);
    qwb[i] = f2bf(qw[i]);
    kwb[i] = f2bf(kw[i]);
    vwb[i] = f2bf(vw[i]);
  }
}

// ---------------- sort by segment: hist / scan / scatter ----------------
__global__ __launch_bounds__(256) void hist_kernel(const int* __restrict__ srcp,
                                                   const int* __restrict__ dstp,
                                                   const int* __restrict__ z,
                                                   int* __restrict__ hist) {
  int e = blockIdx.x * 256 + threadIdx.x;
  int s = srcp[e];
  int seg = dstp[e] * T_TYPES + z[s];
  atomicAdd(&hist[seg], 1);
}

__global__ __launch_bounds__(256) void scan1_kernel(const int* __restrict__ hist,
                                                    int* __restrict__ offs,
                                                    int* __restrict__ bsums) {
  __shared__ int lds[256];
  int tid = threadIdx.x;
  int base = blockIdx.x * 1024 + tid * 4;
  int v[4];
  int s = 0;
#pragma unroll
  for (int i = 0; i < 4; ++i) {
    v[i] = (base + i < NSEG) ? hist[base + i] : 0;
    s += v[i];
  }
  lds[tid] = s;
  __syncthreads();
  for (int d = 1; d < 256; d <<= 1) {
    int t = (tid >= d) ? lds[tid - d] : 0;
    __syncthreads();
    lds[tid] += t;
    __syncthreads();
  }
  int excl = lds[tid] - s;
#pragma unroll
  for (int i = 0; i < 4; ++i) {
    if (base + i < NSEG) offs[base + i] = excl;
    excl += v[i];
  }
  if (tid == 255) bsums[blockIdx.x] = lds[255];
}

__global__ __launch_bounds__(128) void scan2_kernel(int* __restrict__ bsums,
                                                    int nb) {
  __shared__ int lds[128];
  int tid = threadIdx.x;
  int v = (tid < nb) ? bsums[tid] : 0;
  lds[tid] = v;
  __syncthreads();
  for (int d = 1; d < 128; d <<= 1) {
    int t = (tid >= d) ? lds[tid - d] : 0;
    __syncthreads();
    lds[tid] += t;
    __syncthreads();
  }
  if (tid < nb) bsums[tid] = lds[tid] - v;
}

__global__ __launch_bounds__(256) void scan3_kernel(const int* __restrict__ offs,
                                                    const int* __restrict__ bsums,
                                                    int* __restrict__ cursor) {
  int tid = threadIdx.x;
  int base = blockIdx.x * 1024 + tid * 4;
  int add = bsums[blockIdx.x];
#pragma unroll
  for (int i = 0; i < 4; ++i)
    if (base + i < NSEG) cursor[base + i] = offs[base + i] + add;
}

__global__ __launch_bounds__(256) void scatter_kernel(const int* __restrict__ srcp,
                                                      const int* __restrict__ dstp,
                                                      const int* __restrict__ z,
                                                      int* __restrict__ cursor,
                                                      int* __restrict__ perm) {
  int e = blockIdx.x * 256 + threadIdx.x;
  int s = srcp[e];
  int seg = dstp[e] * T_TYPES + z[s];
  int pos = atomicAdd(&cursor[seg], 1);
  perm[pos] = e;
}

// ---------------- xl = x @ lin1_w^T ----------------
__global__ __launch_bounds__(128) void lin1_kernel(const float* __restrict__ x,
                                                   const float* __restrict__ w,
                                                   float* __restrict__ xl) {
  __shared__ float xs[8 * 128];
  int tid = threadIdx.x;
  int n0 = blockIdx.x * 8;
  const float4* xg = (const float4*)(x + (size_t)n0 * 128);
  float4* xs4 = (float4*)xs;
  for (int i = tid; i < 256; i += 128) xs4[i] = xg[i];
  __syncthreads();
  int f = tid;
  float acc[8] = {};
  const float4* w4 = (const float4*)(w + (size_t)f * 128);
  for (int j4 = 0; j4 < 32; ++j4) {
    float4 wv = w4[j4];
#pragma unroll
    for (int n = 0; n < 8; ++n) {
      float4 xv = xs4[n * 32 + j4];
      acc[n] += wv.x * xv.x + wv.y * xv.y + wv.z * xv.z + wv.w * xv.w;
    }
  }
  for (int n = 0; n < 8; ++n) xl[(size_t)(n0 + n) * 128 + f] = acc[n];
}

// ---------------- per-edge filter net (MFMA, sorted) + run-reduced scatter ----
__global__ __launch_bounds__(256, 3) void edge_mfma_kernel(
    const float* __restrict__ edge_attr, const int* __restrict__ srcp,
    const int* __restrict__ dstp, const float* __restrict__ ewp,
    const int* __restrict__ z, const int* __restrict__ perm,
    const ushort* __restrict__ w1b, const float* __restrict__ b1,
    const ushort* __restrict__ w2b, const float* __restrict__ b2,
    const float* __restrict__ xl, float* __restrict__ y) {
  __shared__ ushort hs[128 * 128];  // bf16 h (swizzled) -> later msg (linear)
  __shared__ float sC[128];
  __shared__ int ssrc[128];
  __shared__ int sseg[128];
  __shared__ int sperm[128];
  __shared__ float sb1[128];
  __shared__ float sb2[128];

  const int tid = threadIdx.x;
  const int e0 = blockIdx.x * 128;
  const int lane = tid & 63;
  const int w = tid >> 6;
  const int wm = w >> 1, wn = w & 1;
  const int lr = lane & 15, lh = lane >> 4;

  if (tid < 128) {
    int e = perm[e0 + tid];
    sperm[tid] = e;
    int s = srcp[e];
    ssrc[tid] = s;
    sseg[tid] = dstp[e] * T_TYPES + z[s];
    float wd = ewp[e];
    float c = 0.5f * (__cosf(wd * 0.6283185307179586f) + 1.0f);
    sC[tid] = (wd < 5.0f) ? c : 0.0f;
    sb1[tid] = b1[tid];
    sb2[tid] = b2[tid];
  }
  __syncthreads();

  // ---- GEMM1: h = silu(EA[perm] @ w1^T + b1) -> swizzled LDS bf16 ----
  {
    f32x4 acc[4][4] = {};
#pragma unroll
    for (int ks = 0; ks < 2; ++ks) {
      const int k0 = ks * 32;
      short8 af[4], bfr[4];
#pragma unroll
      for (int fm = 0; fm < 4; ++fm) {
        int erow = sperm[wm * 64 + fm * 16 + lr];
        const float* ap = edge_attr + (size_t)erow * 64 + k0 + lh * 8;
        float4 a0 = *(const float4*)ap;
        float4 a1 = *(const float4*)(ap + 4);
        S8U4 t;
        t.u[0] = cvt_pk(a0.x, a0.y);
        t.u[1] = cvt_pk(a0.z, a0.w);
        t.u[2] = cvt_pk(a1.x, a1.y);
        t.u[3] = cvt_pk(a1.z, a1.w);
        af[fm] = t.s;
      }
#pragma unroll
      for (int fc = 0; fc < 4; ++fc)
        bfr[fc] = *(const short8*)(w1b + (size_t)(wn * 64 + fc * 16 + lr) * 64 +
                                   k0 + lh * 8);
#pragma unroll
      for (int fm = 0; fm < 4; ++fm)
#pragma unroll
        for (int fc = 0; fc < 4; ++fc)
          acc[fm][fc] = __builtin_amdgcn_mfma_f32_16x16x32_bf16(
              af[fm], bfr[fc], acc[fm][fc], 0, 0, 0);
    }
#pragma unroll
    for (int fm = 0; fm < 4; ++fm) {
#pragma unroll
      for (int fc = 0; fc < 4; ++fc) {
#pragma unroll
        for (int rp = 0; rp < 4; rp += 2) {
          int ml0 = wm * 64 + fm * 16 + lh * 4 + rp;
          int ml1 = ml0 + 1;
          int n = wn * 64 + fc * 16 + lr;
          float h0 = silu_f(acc[fm][fc][rp] + sb1[n]);
          float h1 = silu_f(acc[fm][fc][rp + 1] + sb1[n]);
          unsigned u = cvt_pk(h0, h1);
          hs[(ml0 * 256 + ((n * 2) ^ ((ml0 & 7) << 4))) >> 1] = (ushort)u;
          hs[(ml1 * 256 + ((n * 2) ^ ((ml1 & 7) << 4))) >> 1] = (ushort)(u >> 16);
        }
      }
    }
  }
  __syncthreads();

  // ---- GEMM2: W = h @ w2^T + b2 ----
  f32x4 acc2[4][4] = {};
#pragma unroll
  for (int ks = 0; ks < 4; ++ks) {
    const int k0 = ks * 32;
    short8 af[4], bfr[4];
#pragma unroll
    for (int fm = 0; fm < 4; ++fm) {
      int ml = wm * 64 + fm * 16 + lr;
      int byte_in_row = (k0 * 2 + lh * 16) ^ ((ml & 7) << 4);
      af[fm] = *(const short8*)&hs[(ml * 256 + byte_in_row) >> 1];
    }
#pragma unroll
    for (int fc = 0; fc < 4; ++fc)
      bfr[fc] = *(const short8*)(w2b + (size_t)(wn * 64 + fc * 16 + lr) * 128 +
                                 k0 + lh * 8);
#pragma unroll
    for (int fm = 0; fm < 4; ++fm)
#pragma unroll
      for (int fc = 0; fc < 4; ++fc)
        acc2[fm][fc] = __builtin_amdgcn_mfma_f32_16x16x32_bf16(
            af[fm], bfr[fc], acc2[fm][fc], 0, 0, 0);
  }
  __syncthreads();  // all hs reads done

  // msg = (W + b2) * C * xl[src] -> linear LDS bf16
#pragma unroll
  for (int fm = 0; fm < 4; ++fm) {
#pragma unroll
    for (int rp = 0; rp < 4; rp += 2) {
      int ml0 = wm * 64 + fm * 16 + lh * 4 + rp;
      int ml1 = ml0 + 1;
      float c0 = sC[ml0], c1 = sC[ml1];
      const float* xl0 = xl + (size_t)ssrc[ml0] * 128;
      const float* xl1 = xl + (size_t)ssrc[ml1] * 128;
#pragma unroll
      for (int fc = 0; fc < 4; ++fc) {
        int n = wn * 64 + fc * 16 + lr;
        float v0 = (acc2[fm][fc][rp] + sb2[n]) * c0 * xl0[n];
        float v1 = (acc2[fm][fc][rp + 1] + sb2[n]) * c1 * xl1[n];
        unsigned u = cvt_pk(v0, v1);
        hs[ml0 * 128 + n] = (ushort)u;
        hs[ml1 * 128 + n] = (ushort)(u >> 16);
      }
    }
  }
  __syncthreads();

  // run-walk: rows sorted by seg -> one atomic per (run, col).
  // 2 independent 32-row chains per thread for ILP (serial depth 32).
  {
    int col = tid & 127;
    int q = tid >> 7;
    int rA = 32 * q;
    int rB = 64 + 32 * q;
    float accA = 0.0f, accB = 0.0f;
    int curA = sseg[rA], curB = sseg[rB];
    for (int i = 0; i < 32; ++i) {
      int sgA = sseg[rA + i];
      float vA = bf2f(hs[(rA + i) * 128 + col]);
      int sgB = sseg[rB + i];
      float vB = bf2f(hs[(rB + i) * 128 + col]);
      if (sgA != curA) {
        atomicAdd(&y[(size_t)curA * 128 + col], accA);
        accA = 0.0f;
        curA = sgA;
      }
      accA += vA;
      if (sgB != curB) {
        atomicAdd(&y[(size_t)curB * 128 + col], accB);
        accB = 0.0f;
        curB = sgB;
      }
      accB += vB;
    }
    atomicAdd(&y[(size_t)curA * 128 + col], accA);
    atomicAdd(&y[(size_t)curB * 128 + col], accB);
  }
}

// ---------------- fused qkv (MFMA) + attention + slot-sum ----------------
#define QS 136  // padded LDS row stride (ushorts), 272B = 16B-aligned rows
#define NB 16   // nodes per block
__global__ __launch_bounds__(256) void attn_fused_kernel(
    const float* __restrict__ y, const int* __restrict__ hist,
    const ushort* __restrict__ qwb, const ushort* __restrict__ kwb,
    const ushort* __restrict__ vwb, const float* __restrict__ qb,
    const float* __restrict__ kb, const float* __restrict__ vb,
    float* __restrict__ sout) {
  __shared__ ushort qs[80 * QS];
  __shared__ ushort ks_[80 * QS];
  __shared__ ushort vs[80 * QS];
  __shared__ float aa[NB * 8 * 5];
  __shared__ float pmv[80];
  __shared__ float sxb[3][128];

  const int tid = threadIdx.x;
  const int n0 = blockIdx.x * NB;
  const int row0 = n0 * T_TYPES;
  const int lane = tid & 63;
  const int w = tid >> 6;  // wave 0..3 -> col slice w*32
  const int lr = lane & 15, lh = lane >> 4;

  if (tid < 128) {
    sxb[0][tid] = qb[tid];
    sxb[1][tid] = kb[tid];
    sxb[2][tid] = vb[tid];
  }
  if (tid < 80) pmv[tid] = (hist[(size_t)row0 + tid] > 0) ? 1.0f : 0.0f;

  // A fragments (y rows fp32 -> bf16), reused across q/k/v
  short8 A[4][5];
#pragma unroll
  for (int ksi = 0; ksi < 4; ++ksi) {
#pragma unroll
    for (int fm = 0; fm < 5; ++fm) {
      const float* ap =
          y + (size_t)(row0 + fm * 16 + lr) * 128 + ksi * 32 + lh * 8;
      float4 a0 = *(const float4*)ap;
      float4 a1 = *(const float4*)(ap + 4);
      S8U4 t;
      t.u[0] = cvt_pk(a0.x, a0.y);
      t.u[1] = cvt_pk(a0.z, a0.w);
      t.u[2] = cvt_pk(a1.x, a1.y);
      t.u[3] = cvt_pk(a1.z, a1.w);
      A[ksi][fm] = t.s;
    }
  }
  __syncthreads();  // biases/pmv staged

  const ushort* Wp[3] = {qwb, kwb, vwb};
  ushort* Xp[3] = {qs, ks_, vs};
#pragma unroll
  for (int m = 0; m < 3; ++m) {
    f32x4 acc[5][2] = {};
#pragma unroll
    for (int ksi = 0; ksi < 4; ++ksi) {
      short8 B[2];
#pragma unroll
      for (int fc = 0; fc < 2; ++fc)
        B[fc] = *(const short8*)(Wp[m] + (size_t)(w * 32 + fc * 16 + lr) * 128 +
                                 ksi * 32 + lh * 8);
#pragma unroll
      for (int fm = 0; fm < 5; ++fm)
#pragma unroll
        for (int fc = 0; fc < 2; ++fc)
          acc[fm][fc] = __builtin_amdgcn_mfma_f32_16x16x32_bf16(
              A[ksi][fm], B[fc], acc[fm][fc], 0, 0, 0);
    }
#pragma unroll
    for (int fm = 0; fm < 5; ++fm)
#pragma unroll
      for (int fc = 0; fc < 2; ++fc)
#pragma unroll
        for (int rp = 0; rp < 4; rp += 2) {
          int rrow = fm * 16 + lh * 4 + rp;
          int col = w * 32 + fc * 16 + lr;
          float v0 = acc[fm][fc][rp] + sxb[m][col];
          float v1 = acc[fm][fc][rp + 1] + sxb[m][col];
          unsigned u = cvt_pk(v0, v1);
          Xp[m][rrow * QS + col] = (ushort)u;
          Xp[m][(rrow + 1) * QS + col] = (ushort)(u >> 16);
        }
  }
  __syncthreads();

  // attention scores: thread -> (n, h), vector LDS reads
  if (tid < NB * 8) {
    int n = tid >> 3, h = tid & 7;
    float kv[5][16];
#pragma unroll
    for (int j = 0; j < 5; ++j) {
      short8 v0 = *(const short8*)&ks_[(n * 5 + j) * QS + h * 16];
      short8 v1 = *(const short8*)&ks_[(n * 5 + j) * QS + h * 16 + 8];
#pragma unroll
      for (int d = 0; d < 8; ++d) {
        kv[j][d] = bf2f((ushort)v0[d]);
        kv[j][d + 8] = bf2f((ushort)v1[d]);
      }
    }
    float a[5] = {};
    for (int i = 0; i < 5; ++i) {
      float qv[16];
      short8 q0 = *(const short8*)&qs[(n * 5 + i) * QS + h * 16];
      short8 q1 = *(const short8*)&qs[(n * 5 + i) * QS + h * 16 + 8];
#pragma unroll
      for (int d = 0; d < 8; ++d) {
        qv[d] = bf2f((ushort)q0[d]);
        qv[d + 8] = bf2f((ushort)q1[d]);
      }
      float pmi = pmv[n * 5 + i];
#pragma unroll
      for (int j = 0; j < 5; ++j) {
        float dd = 0.0f;
#pragma unroll
        for (int d = 0; d < 16; ++d) dd += qv[d] * kv[j][d];
        a[j] += pmi * silu_f(dd);
      }
    }
#pragma unroll
    for (int j = 0; j < 5; ++j) aa[(n * 8 + h) * 5 + j] = a[j] * pmv[n * 5 + j];
  }
  __syncthreads();

  // s[n][f0..f0+7] = sum_j aa[n][h][j] * v[n][j][f]
  {
    int n = tid >> 4;
    int o = tid & 15;
    int f0 = o * 8;
    int h = f0 >> 4;
    float acc8[8] = {};
#pragma unroll
    for (int j = 0; j < 5; ++j) {
      float a = aa[(n * 8 + h) * 5 + j];
      short8 vv8 = *(const short8*)&vs[(n * 5 + j) * QS + f0];
#pragma unroll
      for (int d = 0; d < 8; ++d) acc8[d] += a * bf2f((ushort)vv8[d]);
    }
    float* op = sout + (size_t)(n0 + n) * 128 + f0;
    *(float4*)op = make_float4(acc8[0], acc8[1], acc8[2], acc8[3]);
    *(float4*)(op + 4) = make_float4(acc8[4], acc8[5], acc8[6], acc8[7]);
  }
}

// ---------------- out = silu((s@o1^T + npm*o1_b) @ o2^T + o2_b) ----------------
__global__ __launch_bounds__(128) void out_kernel(
    const float* __restrict__ sbufg, const int* __restrict__ hist,
    const float* __restrict__ o1w, const float* __restrict__ o1b,
    const float* __restrict__ o2w, const float* __restrict__ o2b,
    float* __restrict__ outp) {
  __shared__ float sb[8 * 128];
  __shared__ float t1[8 * 128];
  __shared__ float npm[8];
  int tid = threadIdx.x;
  int n0 = blockIdx.x * 8;
  const float4* sg4 = (const float4*)(sbufg + (size_t)n0 * 128);
  float4* sb4 = (float4*)sb;
  for (int i = tid; i < 256; i += 128) sb4[i] = sg4[i];
  if (tid < 8) {
    float s = 0.0f;
    for (int t = 0; t < T_TYPES; ++t)
      s += (hist[(size_t)(n0 + tid) * T_TYPES + t] > 0) ? 1.0f : 0.0f;
    npm[tid] = s;
  }
  __syncthreads();
  int f = tid;
  {
    const float4* wg = (const float4*)(o1w + (size_t)f * 128);
    float acc[8] = {};
    for (int j4 = 0; j4 < 32; ++j4) {
      float4 wv = wg[j4];
#pragma unroll
      for (int n = 0; n < 8; ++n) {
        float4 sv = sb4[n * 32 + j4];
        acc[n] += wv.x * sv.x + wv.y * sv.y + wv.z * sv.z + wv.w * sv.w;
      }
    }
    float bb = o1b[f];
    for (int n = 0; n < 8; ++n) t1[n * 128 + f] = acc[n] + npm[n] * bb;
  }
  __syncthreads();
  {
    const float4* wg = (const float4*)(o2w + (size_t)f * 128);
    const float4* t14 = (const float4*)t1;
    float acc[8] = {};
    for (int j4 = 0; j4 < 32; ++j4) {
      float4 wv = wg[j4];
#pragma unroll
      for (int n = 0; n < 8; ++n) {
        float4 tv = t14[n * 32 + j4];
        acc[n] += wv.x * tv.x + wv.y * tv.y + wv.z * tv.z + wv.w * tv.w;
      }
    }
    float bb = o2b[f];
    for (int n = 0; n < 8; ++n) outp[(size_t)(n0 + n) * 128 + f] = silu_f(acc[n] + bb);
  }
}

extern "C" void kernel_launch(void* const* d_in, const int* in_sizes, int n_in,
                              void* d_out, int out_size, void* d_ws, size_t ws_size,
                              hipStream_t stream) {
  const float* x = (const float*)d_in[0];
  const int* z = (const int*)d_in[1];
  const int* ei = (const int*)d_in[2];
  const float* ew = (const float*)d_in[3];
  const float* ea = (const float*)d_in[4];
  const float* lin1_w = (const float*)d_in[5];
  const float* fw1 = (const float*)d_in[6];
  const float* fb1 = (const float*)d_in[7];
  const float* fw2 = (const float*)d_in[8];
  const float* fb2 = (const float*)d_in[9];
  const float* qw = (const float*)d_in[10];
  const float* qb = (const float*)d_in[11];
  const float* kw = (const float*)d_in[12];
  const float* kb = (const float*)d_in[13];
  const float* vw = (const float*)d_in[14];
  const float* vb = (const float*)d_in[15];
  const float* o1w = (const float*)d_in[16];
  const float* o1b = (const float*)d_in[17];
  const float* o2w = (const float*)d_in[18];
  const float* o2b = (const float*)d_in[19];
  float* outp = (float*)d_out;
  float* ws = (float*)d_ws;

  float* xl = ws;                           // N*F  (aliased by sbuf later)
  float* sbuf = xl;                         // alias: xl dead after edge kernel
  float* y = xl + (size_t)N_NODES * F_DIM;  // N*T*F
  ushort* w1b = (ushort*)(y + (size_t)NSEG * F_DIM);
  ushort* w2b = w1b + F_DIM * RBF_DIM;
  ushort* qwb = w2b + F_DIM * F_DIM;
  ushort* kwb = qwb + F_DIM * F_DIM;
  ushort* vwb = kwb + F_DIM * F_DIM;
  int* hist = (int*)(vwb + F_DIM * F_DIM);
  int* offs = hist + NSEG;
  int* cursor = offs + NSEG;
  int* bsums = cursor + NSEG;
  int* perm = bsums + 128;

  const int* srcp = ei;
  const int* dstp = ei + E_EDGES;
  const int NB_SCAN = (NSEG + 1023) / 1024;  // 98

  hipMemsetAsync(y, 0, (size_t)NSEG * F_DIM * sizeof(float), stream);
  hipMemsetAsync(hist, 0, (size_t)NSEG * sizeof(int), stream);

  prep_kernel<<<64, 256, 0, stream>>>(fw1, fw2, qw, kw, vw, w1b, w2b, qwb, kwb, vwb);
  hist_kernel<<<E_EDGES / 256, 256, 0, stream>>>(srcp, dstp, z, hist);
  scan1_kernel<<<NB_SCAN, 256, 0, stream>>>(hist, offs, bsums);
  scan2_kernel<<<1, 128, 0, stream>>>(bsums, NB_SCAN);
  scan3_kernel<<<NB_SCAN, 256, 0, stream>>>(offs, bsums, cursor);
  scatter_kernel<<<E_EDGES / 256, 256, 0, stream>>>(srcp, dstp, z, cursor, perm);
  lin1_kernel<<<N_NODES / 8, 128, 0, stream>>>(x, lin1_w, xl);
  edge_mfma_kernel<<<E_EDGES / 128, 256, 0, stream>>>(ea, srcp, dstp, ew, z, perm,
                                                      w1b, fb1, w2b, fb2, xl, y);
  attn_fused_kernel<<<N_NODES / NB, 256, 0, stream>>>(y, hist, qwb, kwb, vwb, qb,
                                                      kb, vb, sbuf);
  out_kernel<<<N_NODES / 8, 128, 0, stream>>>(sbuf, hist, o1w, o1b, o2w, o2b, outp);
}